// Round 18
// baseline (82.267 us; speedup 1.0000x reference)
//
#include <hip/hip_runtime.h>
#include <stdint.h>

// VectorQuantizer: x[32,64,64,64] NCHW fp32, W[512,64] fp32.
// argmin_k ||x - w_k||^2 ; out = W[argmin] in NCHW.
//
// v18 = v17 fused into ONE dispatch + sweep ILP:
//  - no prep kernel: each wave builds its 8 A-fragments straight from W
//    (f2bf RNE, bitwise-identical to the old image) and computes its 64
//    codes' ||w||^2 in-lane -> nhs in LDS + block wmax^2. No ws image.
//  - T14 prologue order: issue x staging loads (HBM) first, W/L2 work under.
//  - sweep #pragma unroll 2 (two independent iteration chains in flight).
// Proven parts unchanged: swizzled bf16 token LDS, code-slice ownership,
// single-pass max+mask, margin 2^-7*||x||*Wmax+0.02 (certified superset),
// pair-parallel fp64 refine with LDS atomicMin, coalesced epilogue.

typedef short short8 __attribute__((ext_vector_type(8)));
typedef float f32x4 __attribute__((ext_vector_type(4)));
typedef unsigned u32x4 __attribute__((ext_vector_type(4)));

#define HW_ 4096

__device__ __forceinline__ unsigned short f2bf(float f) {
    unsigned u = __float_as_uint(f);
    u += 0x7fff + ((u >> 16) & 1);   // RNE to bf16
    return (unsigned short)(u >> 16);
}

__global__ __launch_bounds__(512, 4) void vq_main(const float* __restrict__ x,
                                                  const float* __restrict__ W,
                                                  float* __restrict__ out) {
    __shared__ unsigned short xb[128 * 64];        // 16 KiB swizzled bf16 tokens
    __shared__ float nhs[512];                     // 2 KiB  -0.5*||w||^2
    __shared__ float wavemax[8][128];              // 4 KiB
    __shared__ unsigned long long cmask[8][128];   // 8 KiB
    __shared__ float xsqpart[4][128];              // 2 KiB
    __shared__ float marginArr[128];               // 0.5 KiB
    __shared__ int bkArr[128];                     // 0.5 KiB
    __shared__ unsigned pairs[1024];               // 4 KiB (tok<<16 | k)
    __shared__ unsigned long long bestKey[128];    // 1 KiB
    __shared__ float red8[8];
    __shared__ int pcnt;

    const int tid = threadIdx.x;
    const int bid = blockIdx.x;
    const int b = bid >> 5;                 // batch 0..31
    const int p0 = (bid & 31) << 7;         // 128-token spatial base
    const int l = tid & 63;
    const int wv = tid >> 6;                // wave 0..7 owns codes wv*64..+63

    if (tid == 0) pcnt = 0;
    if (tid < 128) bestKey[tid] = ~0ull;

    // ---- issue x staging loads first (HBM latency hides under W work) ----
    const int stok = tid & 127;             // token
    const int sq = tid >> 7;                // dim quarter 0..3
    float sv[16];
    {
        const float* xp = x + (size_t)(b * 64 + sq * 16) * HW_ + p0 + stok;
        #pragma unroll
        for (int e = 0; e < 16; ++e) sv[e] = xp[(size_t)e * HW_];
    }

    // ---- per-lane code norm: s = ||w_{wv*64+l}||^2 (L2-hot contiguous) ----
    {
        const float* wr = W + (wv * 64 + l) * 64;
        float s = 0.f;
        #pragma unroll
        for (int i = 0; i < 16; ++i) {
            f32x4 v = *(const f32x4*)(wr + i * 4);
            s += v[0] * v[0] + v[1] * v[1] + v[2] * v[2] + v[3] * v[3];
        }
        nhs[wv * 64 + l] = -0.5f * s;
        #pragma unroll
        for (int off = 1; off < 64; off <<= 1) s = fmaxf(s, __shfl_xor(s, off));
        if (l == 0) red8[wv] = s;
    }

    // ---- A-fragments direct from W: code wv*64 + J*16 + (l&15), dims (l>>4)*8 ----
    short8 a0_0, a0_1, a0_2, a0_3, a1_0, a1_1, a1_2, a1_3;
    {
        const float* base = W + (wv * 64 + (l & 15)) * 64 + (l >> 4) * 8;
        #pragma unroll
        for (int J = 0; J < 4; ++J) {
            f32x4 v0 = *(const f32x4*)(base + J * 16 * 64);
            f32x4 v1 = *(const f32x4*)(base + J * 16 * 64 + 4);
            f32x4 v2 = *(const f32x4*)(base + J * 16 * 64 + 32);
            f32x4 v3 = *(const f32x4*)(base + J * 16 * 64 + 36);
            short8 lo, hi;
            #pragma unroll
            for (int e = 0; e < 4; ++e) {
                lo[e] = (short)f2bf(v0[e]); lo[e + 4] = (short)f2bf(v1[e]);
                hi[e] = (short)f2bf(v2[e]); hi[e + 4] = (short)f2bf(v3[e]);
            }
            if (J == 0) { a0_0 = lo; a1_0 = hi; }
            else if (J == 1) { a0_1 = lo; a1_1 = hi; }
            else if (J == 2) { a0_2 = lo; a1_2 = hi; }
            else { a0_3 = lo; a1_3 = hi; }
        }
    }

    // ---- pack + write staged tokens (swizzled), xsq partials ----
    {
        float xsq = 0.f;
        u32x4 pk0, pk1;
        #pragma unroll
        for (int p = 0; p < 4; ++p) {
            xsq += sv[2*p]*sv[2*p] + sv[2*p+1]*sv[2*p+1]
                 + sv[8+2*p]*sv[8+2*p] + sv[9+2*p]*sv[9+2*p];
            pk0[p] = (unsigned)f2bf(sv[2*p])   | ((unsigned)f2bf(sv[2*p+1]) << 16);
            pk1[p] = (unsigned)f2bf(sv[8+2*p]) | ((unsigned)f2bf(sv[9+2*p]) << 16);
        }
        const int s0 = (sq * 2)     ^ (stok & 7);
        const int s1 = (sq * 2 + 1) ^ (stok & 7);
        *(u32x4*)((char*)xb + stok * 128 + s0 * 16) = pk0;
        *(u32x4*)((char*)xb + stok * 128 + s1 * 16) = pk1;
        xsqpart[sq][stok] = xsq;
    }
    __syncthreads();

    // ---- margin per token ----
    if (tid < 128) {
        float wm2 = red8[0];
        #pragma unroll
        for (int w = 1; w < 8; ++w) wm2 = fmaxf(wm2, red8[w]);
        const float xsq = xsqpart[0][tid] + xsqpart[1][tid] + xsqpart[2][tid] + xsqpart[3][tid];
        marginArr[tid] = ldexpf(sqrtf(xsq * wm2), -7) + 0.02f;   // 2E certified
    }
    // nh C-inits from LDS (broadcast reads)
    f32x4 nhv0, nhv1, nhv2, nhv3;
    __syncthreads();
    {
        const float* np = nhs + wv * 64 + (l >> 4) * 4;
        nhv0 = *(const f32x4*)(np);
        nhv1 = *(const f32x4*)(np + 16);
        nhv2 = *(const f32x4*)(np + 32);
        nhv3 = *(const f32x4*)(np + 48);
    }

    // lane-constant swizzled byte offsets (tok&7 == l&7 within every group)
    const int off0 = (((l >> 4)    ) ^ (l & 7)) * 16;
    const int off1 = (((l >> 4) + 4) ^ (l & 7)) * 16;
    const char* xbB = (const char*)xb + (l & 15) * 128;
    const int rowbase = (l >> 4) * 4;

    // ---- single sweep: scores -> wave max + candidate mask per token ----
    #pragma unroll 2
    for (int g16 = 0; g16 < 8; ++g16) {
        const float marg = marginArr[g16 * 16 + (l & 15)];
        short8 b0 = *(const short8*)(xbB + g16 * 2048 + off0);
        short8 b1 = *(const short8*)(xbB + g16 * 2048 + off1);
        f32x4 c0 = nhv0, c1 = nhv1, c2 = nhv2, c3 = nhv3;
        c0 = __builtin_amdgcn_mfma_f32_16x16x32_bf16(a0_0, b0, c0, 0, 0, 0);
        c1 = __builtin_amdgcn_mfma_f32_16x16x32_bf16(a0_1, b0, c1, 0, 0, 0);
        c2 = __builtin_amdgcn_mfma_f32_16x16x32_bf16(a0_2, b0, c2, 0, 0, 0);
        c3 = __builtin_amdgcn_mfma_f32_16x16x32_bf16(a0_3, b0, c3, 0, 0, 0);
        c0 = __builtin_amdgcn_mfma_f32_16x16x32_bf16(a1_0, b1, c0, 0, 0, 0);
        c1 = __builtin_amdgcn_mfma_f32_16x16x32_bf16(a1_1, b1, c1, 0, 0, 0);
        c2 = __builtin_amdgcn_mfma_f32_16x16x32_bf16(a1_2, b1, c2, 0, 0, 0);
        c3 = __builtin_amdgcn_mfma_f32_16x16x32_bf16(a1_3, b1, c3, 0, 0, 0);

        float mm = fmaxf(fmaxf(fmaxf(c0[0], c0[1]), fmaxf(c0[2], c0[3])),
                         fmaxf(fmaxf(c1[0], c1[1]), fmaxf(c1[2], c1[3])));
        mm = fmaxf(mm, fmaxf(fmaxf(c2[0], c2[1]), fmaxf(c2[2], c2[3])));
        mm = fmaxf(mm, fmaxf(fmaxf(c3[0], c3[1]), fmaxf(c3[2], c3[3])));
        mm = fmaxf(mm, __shfl_xor(mm, 16));
        mm = fmaxf(mm, __shfl_xor(mm, 32));
        const float thr = mm - marg;

        unsigned long long msk = 0;
        unsigned b4 = 0;
        #pragma unroll
        for (int r = 0; r < 4; ++r) b4 |= (c0[r] >= thr ? 1u : 0u) << r;
        msk |= (unsigned long long)b4 << (0 * 16 + rowbase);
        b4 = 0;
        #pragma unroll
        for (int r = 0; r < 4; ++r) b4 |= (c1[r] >= thr ? 1u : 0u) << r;
        msk |= (unsigned long long)b4 << (1 * 16 + rowbase);
        b4 = 0;
        #pragma unroll
        for (int r = 0; r < 4; ++r) b4 |= (c2[r] >= thr ? 1u : 0u) << r;
        msk |= (unsigned long long)b4 << (2 * 16 + rowbase);
        b4 = 0;
        #pragma unroll
        for (int r = 0; r < 4; ++r) b4 |= (c3[r] >= thr ? 1u : 0u) << r;
        msk |= (unsigned long long)b4 << (3 * 16 + rowbase);

        msk |= __shfl_xor(msk, 16);
        msk |= __shfl_xor(msk, 32);
        if (l < 16) {
            wavemax[wv][g16 * 16 + l] = mm;
            cmask[wv][g16 * 16 + l] = msk;
        }
    }
    __syncthreads();

    // ---- resolution: singleton inline; multi -> flat pair list ----
    if (tid < 128) {
        const int tok = tid;
        float gm = wavemax[0][tok];
        #pragma unroll
        for (int w = 1; w < 8; ++w) gm = fmaxf(gm, wavemax[w][tok]);
        const float thr = gm - marginArr[tok];
        int cnt = 0;
        int bk = -1;
        #pragma unroll
        for (int w = 0; w < 8; ++w) {
            if (wavemax[w][tok] >= thr) {
                unsigned long long mmm = cmask[w][tok];
                cnt += __popcll(mmm);
                if (mmm) bk = w * 64 + __builtin_ctzll(mmm);
            }
        }
        if (cnt == 1) {
            bkArr[tok] = bk;                // certified exact argmin
        } else {
            #pragma unroll
            for (int w = 0; w < 8; ++w) {
                if (wavemax[w][tok] < thr) continue;
                unsigned long long mmm = cmask[w][tok];
                while (mmm) {
                    const int bit = __builtin_ctzll(mmm); mmm &= mmm - 1;
                    const int k = w * 64 + bit;
                    const int idx = atomicAdd(&pcnt, 1);
                    if (idx < 1024) {
                        pairs[idx] = ((unsigned)tok << 16) | (unsigned)k;
                    } else {                 // statistically-never fallback
                        const float* xc = x + (size_t)b * 262144 + p0 + tok;
                        const float* wr = W + k * 64;
                        double acc = 0.0;
                        #pragma unroll 1
                        for (int d = 0; d < 64; ++d) {
                            double dl = (double)xc[(size_t)d * HW_] - (double)wr[d];
                            acc = fma(dl, dl, acc);
                        }
                        unsigned long long key =
                            (__double_as_longlong(acc) & ~1023ull) | (unsigned long long)k;
                        atomicMin(&bestKey[tok], key);
                    }
                }
            }
        }
    }
    __syncthreads();

    // ---- pair-parallel exact fp64 refine: one lane per (tok,k) pair ----
    {
        const int nP = min(pcnt, 1024);
        for (int i = tid; i < nP; i += 512) {
            const unsigned pr = pairs[i];
            const int tok = pr >> 16;
            const int k = pr & 0xffff;
            const float* xc = x + (size_t)b * 262144 + p0 + tok;
            const float* wr = W + k * 64;
            double acc = 0.0;
            #pragma unroll
            for (int d = 0; d < 64; ++d) {
                double dl = (double)xc[(size_t)d * HW_] - (double)wr[d];
                acc = fma(dl, dl, acc);
            }
            unsigned long long key =
                (__double_as_longlong(acc) & ~1023ull) | (unsigned long long)k;
            atomicMin(&bestKey[tok], key);
        }
    }
    __syncthreads();
    if (tid < 128 && bestKey[tid] != ~0ull)
        bkArr[tid] = (int)(bestKey[tid] & 1023ull);
    __syncthreads();

    // ---- epilogue: gather W rows (L2-hot), coalesced NCHW store ----
    {
        const int pp = tid & 127;            // token
        const int dq = tid >> 7;             // dim quarter 0..3
        const int kk = bkArr[pp];
        const float* wr = W + kk * 64 + dq * 16;
        float* ob = out + (size_t)b * 262144 + p0 + pp;
        #pragma unroll
        for (int j = 0; j < 4; ++j) {
            f32x4 v = *(const f32x4*)(wr + j * 4);
            ob[(size_t)(dq * 16 + j * 4 + 0) * HW_] = v[0];
            ob[(size_t)(dq * 16 + j * 4 + 1) * HW_] = v[1];
            ob[(size_t)(dq * 16 + j * 4 + 2) * HW_] = v[2];
            ob[(size_t)(dq * 16 + j * 4 + 3) * HW_] = v[3];
        }
    }
}

extern "C" void kernel_launch(void* const* d_in, const int* in_sizes, int n_in,
                              void* d_out, int out_size, void* d_ws, size_t ws_size,
                              hipStream_t stream) {
    const float* x = (const float*)d_in[0];
    const float* W = (const float*)d_in[1];
    vq_main<<<1024, 512, 0, stream>>>(x, W, (float*)d_out);
}

// Round 19
// 68.831 us; speedup vs baseline: 1.1952x; 1.1952x over previous
//
#include <hip/hip_runtime.h>
#include <stdint.h>

// VectorQuantizer: x[32,64,64,64] NCHW fp32, W[512,64] fp32.
// argmin_k ||x - w_k||^2 ; out = W[argmin] in NCHW.
//
// v19: token-ownership with 32x32x16 MFMA, 2 barriers total.
// 512-thr blocks (8 waves x 32 tokens = 256 tokens/block, grid 512).
// Codebook image in LDS (64 KiB, v6-verified layout); B-frags (tokens) in
// 16 VGPRs direct from global; 16 tiles x 4 MFMA, 2-pass max->mask;
// margin 2^-7*||x||*Wmax+0.02 (certified); singleton exact; multi ->
// per-wave ballot-walk fp64 refine (lanes=dims). No cross-wave merge.

typedef short short8 __attribute__((ext_vector_type(8)));
typedef float f32x4 __attribute__((ext_vector_type(4)));
typedef float f32x8 __attribute__((ext_vector_type(8)));
typedef float f32x16 __attribute__((ext_vector_type(16)));

#define HW_ 4096

__device__ __forceinline__ unsigned short f2bf(float f) {
    unsigned u = __float_as_uint(f);
    u += 0x7fff + ((u >> 16) & 1);   // RNE to bf16
    return (unsigned short)(u >> 16);
}

// Image: ushort idx(k,d) = (d>>3)*4096 + k*8 + (d&7)   [8 octet-planes]
__global__ __launch_bounds__(64) void vq_prep(const float* __restrict__ W,
                                              unsigned short* __restrict__ Wb,
                                              float* __restrict__ nh) {
    const int k = blockIdx.x, l = threadIdx.x;
    float v = W[k * 64 + l];
    Wb[(l >> 3) * 4096 + k * 8 + (l & 7)] = f2bf(v);
    float s = v * v;
    #pragma unroll
    for (int off = 1; off < 64; off <<= 1) s += __shfl_xor(s, off);
    if (l == 0) nh[k] = -0.5f * s;
}

__global__ __launch_bounds__(512, 4) void vq_main(const float* __restrict__ x,
                                                  const float* __restrict__ W,
                                                  const unsigned short* __restrict__ Wb,
                                                  const float* __restrict__ nh,
                                                  float* __restrict__ out) {
    __shared__ unsigned short cb[32768];   // 64 KiB codebook image
    __shared__ float nhs[512];             // -0.5*||w||^2
    __shared__ int bkArr[256];
    __shared__ float red8[8];

    const int tid = threadIdx.x;
    const int bid = blockIdx.x;
    const int b = bid >> 4;                 // batch 0..31
    const int p0 = (bid & 15) << 8;         // 256-token spatial base
    const int l = tid & 63;
    const int wv = tid >> 6;                // wave 0..7 owns tokens wv*32..+31
    const int hi = l >> 5;
    const int col = l & 31;
    const int tok = wv * 32 + col;          // block token 0..255

    // ---- stage codebook image + nhs (linear, conflict-free) ----
    {
        const f32x4* src = (const f32x4*)Wb;
        f32x4* dst = (f32x4*)cb;
        #pragma unroll
        for (int i = 0; i < 8; ++i) dst[tid + i * 512] = src[tid + i * 512];
        nhs[tid] = nh[tid];
    }

    // ---- wmax^2: wave wv reduces nh[wv*64..+63] ----
    {
        float s = -2.0f * nh[wv * 64 + l];
        #pragma unroll
        for (int off = 1; off < 64; off <<= 1) s = fmaxf(s, __shfl_xor(s, off));
        if (l == 0) red8[wv] = s;
    }

    // ---- B fragments direct from global (dims kt*16 + hi*8 + e); xsq ----
    short8 bf0, bf1, bf2, bf3;
    float xsq = 0.f;
    {
        const float* xp = x + (size_t)(b * 64) * HW_ + p0 + tok;
        #pragma unroll
        for (int e = 0; e < 8; ++e) {
            float v0 = xp[(size_t)(hi * 8 + e) * HW_];
            float v1 = xp[(size_t)(16 + hi * 8 + e) * HW_];
            float v2 = xp[(size_t)(32 + hi * 8 + e) * HW_];
            float v3 = xp[(size_t)(48 + hi * 8 + e) * HW_];
            xsq += v0 * v0 + v1 * v1 + v2 * v2 + v3 * v3;
            bf0[e] = (short)f2bf(v0);
            bf1[e] = (short)f2bf(v1);
            bf2[e] = (short)f2bf(v2);
            bf3[e] = (short)f2bf(v3);
        }
    }
    xsq += __shfl_xor(xsq, 32);
    __syncthreads();                        // cb, nhs, red8 ready

    float wm2 = red8[0];
    #pragma unroll
    for (int w = 1; w < 8; ++w) wm2 = fmaxf(wm2, red8[w]);
    const float margin = ldexpf(sqrtf(xsq * wm2), -7) + 0.02f;   // 2E certified

    const char* Ab = (const char*)cb + hi * 8192 + col * 16;

    #define BUILD_ACC(T, ACC) \
        f32x4 q0 = *(const f32x4*)(&nhs[(T) * 32 + hi * 4]); \
        f32x4 q1 = *(const f32x4*)(&nhs[(T) * 32 + hi * 4 + 8]); \
        f32x4 q2 = *(const f32x4*)(&nhs[(T) * 32 + hi * 4 + 16]); \
        f32x4 q3 = *(const f32x4*)(&nhs[(T) * 32 + hi * 4 + 24]); \
        f32x8 h0 = __builtin_shufflevector(q0, q1, 0, 1, 2, 3, 4, 5, 6, 7); \
        f32x8 h1 = __builtin_shufflevector(q2, q3, 0, 1, 2, 3, 4, 5, 6, 7); \
        f32x16 ACC = __builtin_shufflevector(h0, h1, 0, 1, 2, 3, 4, 5, 6, 7, \
                                             8, 9, 10, 11, 12, 13, 14, 15); \
        { \
            short8 a0 = *(const short8*)(Ab + (T) * 512); \
            short8 a1 = *(const short8*)(Ab + (T) * 512 + 16384); \
            short8 a2 = *(const short8*)(Ab + (T) * 512 + 32768); \
            short8 a3 = *(const short8*)(Ab + (T) * 512 + 49152); \
            ACC = __builtin_amdgcn_mfma_f32_32x32x16_bf16(a0, bf0, ACC, 0, 0, 0); \
            ACC = __builtin_amdgcn_mfma_f32_32x32x16_bf16(a1, bf1, ACC, 0, 0, 0); \
            ACC = __builtin_amdgcn_mfma_f32_32x32x16_bf16(a2, bf2, ACC, 0, 0, 0); \
            ACC = __builtin_amdgcn_mfma_f32_32x32x16_bf16(a3, bf3, ACC, 0, 0, 0); \
        }

    // ---- pass 1: running per-lane max over all 16 tiles ----
    float runm = -3.4e38f;
    #pragma unroll 1
    for (int T = 0; T < 16; ++T) {
        BUILD_ACC(T, acc);
        float m01 = fmaxf(fmaxf(acc[0], acc[1]), fmaxf(acc[2], acc[3]));
        float m23 = fmaxf(fmaxf(acc[4], acc[5]), fmaxf(acc[6], acc[7]));
        float m45 = fmaxf(fmaxf(acc[8], acc[9]), fmaxf(acc[10], acc[11]));
        float m67 = fmaxf(fmaxf(acc[12], acc[13]), fmaxf(acc[14], acc[15]));
        runm = fmaxf(runm, fmaxf(fmaxf(m01, m23), fmaxf(m45, m67)));
    }
    const float mm = fmaxf(runm, __shfl_xor(runm, 32));   // per-token max (512 codes)
    const float thr = mm - margin;

    // ---- pass 2: per-lane candidate masks (bit = T*16 + reg) ----
    uint64_t m0 = 0, m1 = 0, m2 = 0, m3 = 0;
    #pragma unroll 1
    for (int w4 = 0; w4 < 4; ++w4) {
        uint64_t a64 = 0;
        #pragma unroll
        for (int t2 = 0; t2 < 4; ++t2) {
            const int T = w4 * 4 + t2;
            BUILD_ACC(T, acc);
            unsigned mt = 0;
            #pragma unroll
            for (int r = 0; r < 16; ++r) mt |= (acc[r] >= thr ? 1u : 0u) << r;
            a64 |= (uint64_t)mt << (t2 * 16);
        }
        if (w4 == 0) m0 = a64;
        else if (w4 == 1) m1 = a64;
        else if (w4 == 2) m2 = a64;
        else m3 = a64;
    }
    #undef BUILD_ACC

    // ---- resolution (wave-local; lanes l and l+32 share a token) ----
    const int cnt = __popcll(m0) + __popcll(m1) + __popcll(m2) + __popcll(m3);
    const int cntT = cnt + __shfl_xor(cnt, 32);

    int klocal = 0x7fffffff;
    if (cnt == 1) {
        int idx = 0;
        if (m0) idx = __builtin_ctzll(m0);
        if (m1) idx = 64 + __builtin_ctzll(m1);
        if (m2) idx = 128 + __builtin_ctzll(m2);
        if (m3) idx = 192 + __builtin_ctzll(m3);
        const int T = idx >> 4, reg = idx & 15;
        klocal = T * 32 + (reg & 3) + 8 * (reg >> 2) + 4 * hi;
    }
    const int kmin = min(klocal, __shfl_xor(klocal, 32));

    double bd = 1.0e308;
    int bkm = 0x7fffffff;
    const bool multi = (cntT > 1);
    if (!multi) { m0 = 0; m1 = 0; m2 = 0; m3 = 0; }
    uint64_t wmask = __ballot((m0 | m1 | m2 | m3) != 0ull);
    while (wmask) {
        const int L = __builtin_ctzll(wmask);
        wmask &= wmask - 1;
        const int hiL = L >> 5;
        const int tokL = wv * 32 + (L & 31);
        const double xvd = (double)x[(size_t)(b * 64 + l) * HW_ + p0 + tokL];
        #pragma unroll 1
        for (int w4 = 0; w4 < 4; ++w4) {
            uint64_t mw = (w4 == 0) ? m0 : (w4 == 1) ? m1 : (w4 == 2) ? m2 : m3;
            uint64_t mmL = __shfl(mw, L);
            while (mmL) {
                const int bit = __builtin_ctzll(mmL); mmL &= mmL - 1;
                const int idx = w4 * 64 + bit;
                const int T = idx >> 4, reg = idx & 15;
                const int k = T * 32 + (reg & 3) + 8 * (reg >> 2) + 4 * hiL;
                double dl = xvd - (double)W[k * 64 + l];
                double p = dl * dl;
                #pragma unroll
                for (int off = 1; off < 64; off <<= 1) p += __shfl_xor(p, off);
                if (l == L && (p < bd || (p == bd && k < bkm))) { bd = p; bkm = k; }
            }
        }
    }
    {   // lexicographic merge across the token's hi-pair
        double od = __shfl_xor(bd, 32); int ok = __shfl_xor(bkm, 32);
        if (od < bd || (od == bd && ok < bkm)) { bd = od; bkm = ok; }
    }
    const int bk = multi ? bkm : kmin;
    if (hi == 0) bkArr[tok] = bk;
    __syncthreads();

    // ---- epilogue: gather W rows (L2-hot), coalesced NCHW store ----
    {
        const int pp = tid & 255;            // token
        const int dh = tid >> 8;             // dim half 0..1
        const int kk = bkArr[pp];
        const float* wr = W + kk * 64 + dh * 32;
        float* ob = out + (size_t)b * 262144 + p0 + pp;
        #pragma unroll
        for (int j = 0; j < 8; ++j) {
            f32x4 v = *(const f32x4*)(wr + j * 4);
            ob[(size_t)(dh * 32 + j * 4 + 0) * HW_] = v[0];
            ob[(size_t)(dh * 32 + j * 4 + 1) * HW_] = v[1];
            ob[(size_t)(dh * 32 + j * 4 + 2) * HW_] = v[2];
            ob[(size_t)(dh * 32 + j * 4 + 3) * HW_] = v[3];
        }
    }
}

extern "C" void kernel_launch(void* const* d_in, const int* in_sizes, int n_in,
                              void* d_out, int out_size, void* d_ws, size_t ws_size,
                              hipStream_t stream) {
    const float* x = (const float*)d_in[0];
    const float* W = (const float*)d_in[1];
    unsigned short* Wb = (unsigned short*)d_ws;              // 64 KiB image
    float* nh = (float*)((char*)d_ws + 65536);               // 512 f32
    vq_prep<<<512, 64, 0, stream>>>(W, Wb, nh);
    vq_main<<<512, 512, 0, stream>>>(x, W, Wb, nh, (float*)d_out);
}

// Round 20
// 62.128 us; speedup vs baseline: 1.3242x; 1.1079x over previous
//
#include <hip/hip_runtime.h>
#include <stdint.h>

// VectorQuantizer: x[32,64,64,64] NCHW fp32, W[512,64] fp32.
// argmin_k ||x - w_k||^2 ; out = W[argmin] in NCHW.
//
// FINAL (= v15, best measured: 62 us headline / 52 us steady, absmax 0).
// 512-thr blocks (8 waves), 128 tokens/block, grid 1024 (4 blocks/CU).
// Wave w holds A-frags of codes w*64..+63 in 32 VGPRs (from prep image);
// tokens staged once in XOR-swizzled bf16 LDS. Single sweep: 8 MFMA ->
// wave max AND candidate mask (>= mm - margin_tok) per iteration.
// Resolution qualifies waves by m_w >= gmax - margin (certified superset);
// singleton -> provably exact argmin; multi -> worklist -> whole-wave
// fp64 refine (lanes = dims, ascending k, strict < = first-index ties).
// Margin 2^-7*||x||*Wmax + 0.02 >= 2*(worst-case bf16 MFMA score error).

typedef short short8 __attribute__((ext_vector_type(8)));
typedef float f32x4 __attribute__((ext_vector_type(4)));
typedef unsigned u32x4 __attribute__((ext_vector_type(4)));

#define HW_ 4096

__device__ __forceinline__ unsigned short f2bf(float f) {
    unsigned u = __float_as_uint(f);
    u += 0x7fff + ((u >> 16) & 1);   // RNE to bf16
    return (unsigned short)(u >> 16);
}

// Image: ushort idx(k,d) = (d>>3)*4096 + k*8 + (d&7)   [8 octet-planes]
__global__ __launch_bounds__(64) void vq_prep(const float* __restrict__ W,
                                              unsigned short* __restrict__ Wb,
                                              float* __restrict__ nh,
                                              int* __restrict__ wmax2i) {
    const int k = blockIdx.x, l = threadIdx.x;
    float v = W[k * 64 + l];
    Wb[(l >> 3) * 4096 + k * 8 + (l & 7)] = f2bf(v);
    float s = v * v;
    #pragma unroll
    for (int off = 1; off < 64; off <<= 1) s += __shfl_xor(s, off);
    if (l == 0) {
        nh[k] = -0.5f * s;
        atomicMax(wmax2i, __float_as_int(s));
    }
}

__global__ __launch_bounds__(512, 4) void vq_main(const float* __restrict__ x,
                                                  const float* __restrict__ W,
                                                  const unsigned short* __restrict__ Wb,
                                                  const float* __restrict__ nh,
                                                  const int* __restrict__ wmax2i,
                                                  float* __restrict__ out) {
    __shared__ unsigned short xb[128 * 64];        // 16 KiB swizzled bf16 tokens
    __shared__ float wavemax[8][128];              // 4 KiB
    __shared__ unsigned long long cmask[8][128];   // 8 KiB
    __shared__ float xsqpart[4][128];              // 2 KiB
    __shared__ float marginArr[128];               // 0.5 KiB
    __shared__ float thrArr[128];                  // 0.5 KiB
    __shared__ int bkArr[128];                     // 0.5 KiB
    __shared__ int wlist[128];                     // 0.5 KiB
    __shared__ int wcnt;

    const int tid = threadIdx.x;
    const int bid = blockIdx.x;
    const int b = bid >> 5;                 // batch 0..31
    const int p0 = (bid & 31) << 7;         // 128-token spatial base
    const int l = tid & 63;
    const int wv = tid >> 6;                // wave 0..7 owns codes wv*64..+63

    if (tid == 0) wcnt = 0;

    // ---- this wave's A-fragments (4 tiles) + nh C-inits, in registers ----
    short8 a0_0, a0_1, a0_2, a0_3, a1_0, a1_1, a1_2, a1_3;
    f32x4 nhv0, nhv1, nhv2, nhv3;
    {
        const unsigned short* Ap = Wb + (l >> 4) * 4096 + ((wv * 4) * 16 + (l & 15)) * 8;
        const unsigned short* Aq = Ap + 4 * 4096;
        a0_0 = *(const short8*)(Ap);        a1_0 = *(const short8*)(Aq);
        a0_1 = *(const short8*)(Ap + 128);  a1_1 = *(const short8*)(Aq + 128);
        a0_2 = *(const short8*)(Ap + 256);  a1_2 = *(const short8*)(Aq + 256);
        a0_3 = *(const short8*)(Ap + 384);  a1_3 = *(const short8*)(Aq + 384);
        const float* np = nh + (wv * 4) * 16 + (l >> 4) * 4;
        nhv0 = *(const f32x4*)(np);
        nhv1 = *(const f32x4*)(np + 16);
        nhv2 = *(const f32x4*)(np + 32);
        nhv3 = *(const f32x4*)(np + 48);
    }

    // ---- stage 128 tokens into swizzled LDS; xsq partials ----
    {
        const int tok = tid & 127;
        const int q = tid >> 7;              // dim quarter 0..3
        const float* xp = x + (size_t)(b * 64 + q * 16) * HW_ + p0 + tok;
        float xsq = 0.f;
        float v[16];
        #pragma unroll
        for (int e = 0; e < 16; ++e) {
            v[e] = xp[(size_t)e * HW_];
            xsq += v[e] * v[e];
        }
        u32x4 pk0, pk1;
        #pragma unroll
        for (int p = 0; p < 4; ++p) {
            pk0[p] = (unsigned)f2bf(v[2 * p])     | ((unsigned)f2bf(v[2 * p + 1]) << 16);
            pk1[p] = (unsigned)f2bf(v[8 + 2 * p]) | ((unsigned)f2bf(v[9 + 2 * p]) << 16);
        }
        const int s0 = (q * 2)     ^ (tok & 7);
        const int s1 = (q * 2 + 1) ^ (tok & 7);
        *(u32x4*)((char*)xb + tok * 128 + s0 * 16) = pk0;
        *(u32x4*)((char*)xb + tok * 128 + s1 * 16) = pk1;
        xsqpart[q][tok] = xsq;
    }
    const float wm2 = __int_as_float(*wmax2i);
    __syncthreads();
    if (tid < 128) {
        const float xsq = xsqpart[0][tid] + xsqpart[1][tid] + xsqpart[2][tid] + xsqpart[3][tid];
        marginArr[tid] = ldexpf(sqrtf(xsq * wm2), -7) + 0.02f;   // 2E certified
    }
    __syncthreads();

    // lane-constant swizzled byte offsets (tok&7 == l&7 within every group)
    const int off0 = (((l >> 4)    ) ^ (l & 7)) * 16;
    const int off1 = (((l >> 4) + 4) ^ (l & 7)) * 16;
    const char* xbB = (const char*)xb + (l & 15) * 128;
    const int rowbase = (l >> 4) * 4;

    // ---- single sweep: scores -> wave max + candidate mask per token ----
    #pragma unroll 1
    for (int g16 = 0; g16 < 8; ++g16) {
        const float marg = marginArr[g16 * 16 + (l & 15)];
        short8 b0 = *(const short8*)(xbB + g16 * 2048 + off0);
        short8 b1 = *(const short8*)(xbB + g16 * 2048 + off1);
        f32x4 c0 = nhv0, c1 = nhv1, c2 = nhv2, c3 = nhv3;
        c0 = __builtin_amdgcn_mfma_f32_16x16x32_bf16(a0_0, b0, c0, 0, 0, 0);
        c1 = __builtin_amdgcn_mfma_f32_16x16x32_bf16(a0_1, b0, c1, 0, 0, 0);
        c2 = __builtin_amdgcn_mfma_f32_16x16x32_bf16(a0_2, b0, c2, 0, 0, 0);
        c3 = __builtin_amdgcn_mfma_f32_16x16x32_bf16(a0_3, b0, c3, 0, 0, 0);
        c0 = __builtin_amdgcn_mfma_f32_16x16x32_bf16(a1_0, b1, c0, 0, 0, 0);
        c1 = __builtin_amdgcn_mfma_f32_16x16x32_bf16(a1_1, b1, c1, 0, 0, 0);
        c2 = __builtin_amdgcn_mfma_f32_16x16x32_bf16(a1_2, b1, c2, 0, 0, 0);
        c3 = __builtin_amdgcn_mfma_f32_16x16x32_bf16(a1_3, b1, c3, 0, 0, 0);

        float mm = fmaxf(fmaxf(fmaxf(c0[0], c0[1]), fmaxf(c0[2], c0[3])),
                         fmaxf(fmaxf(c1[0], c1[1]), fmaxf(c1[2], c1[3])));
        mm = fmaxf(mm, fmaxf(fmaxf(c2[0], c2[1]), fmaxf(c2[2], c2[3])));
        mm = fmaxf(mm, fmaxf(fmaxf(c3[0], c3[1]), fmaxf(c3[2], c3[3])));
        mm = fmaxf(mm, __shfl_xor(mm, 16));
        mm = fmaxf(mm, __shfl_xor(mm, 32));
        const float thr = mm - marg;

        unsigned long long msk = 0;
        unsigned b4 = 0;
        #pragma unroll
        for (int r = 0; r < 4; ++r) b4 |= (c0[r] >= thr ? 1u : 0u) << r;
        msk |= (unsigned long long)b4 << (0 * 16 + rowbase);
        b4 = 0;
        #pragma unroll
        for (int r = 0; r < 4; ++r) b4 |= (c1[r] >= thr ? 1u : 0u) << r;
        msk |= (unsigned long long)b4 << (1 * 16 + rowbase);
        b4 = 0;
        #pragma unroll
        for (int r = 0; r < 4; ++r) b4 |= (c2[r] >= thr ? 1u : 0u) << r;
        msk |= (unsigned long long)b4 << (2 * 16 + rowbase);
        b4 = 0;
        #pragma unroll
        for (int r = 0; r < 4; ++r) b4 |= (c3[r] >= thr ? 1u : 0u) << r;
        msk |= (unsigned long long)b4 << (3 * 16 + rowbase);

        msk |= __shfl_xor(msk, 16);
        msk |= __shfl_xor(msk, 32);
        if (l < 16) {
            wavemax[wv][g16 * 16 + l] = mm;
            cmask[wv][g16 * 16 + l] = msk;
        }
    }
    __syncthreads();

    // ---- resolution: qualify waves, singleton inline; multi -> worklist ----
    if (tid < 128) {
        const int tok = tid;
        float gm = wavemax[0][tok];
        #pragma unroll
        for (int w = 1; w < 8; ++w) gm = fmaxf(gm, wavemax[w][tok]);
        const float thr = gm - marginArr[tok];
        thrArr[tok] = thr;
        int cnt = 0;
        int bk = -1;
        #pragma unroll
        for (int w = 0; w < 8; ++w) {
            if (wavemax[w][tok] >= thr) {
                unsigned long long mmm = cmask[w][tok];
                cnt += __popcll(mmm);
                if (mmm) bk = w * 64 + __builtin_ctzll(mmm);
            }
        }
        if (cnt == 1) bkArr[tok] = bk;      // certified exact argmin
        else wlist[atomicAdd(&wcnt, 1)] = tok;
    }
    __syncthreads();

    // ---- wave-cooperative fp64 refine over the worklist ----
    {
        const int nW = wcnt;
        for (int i = wv; i < nW; i += 8) {
            const int tok = wlist[i];
            const float thr = thrArr[tok];
            const double xl = (double)x[(size_t)(b * 64 + l) * HW_ + p0 + tok];
            double bd = 1.0e308;
            int bk = 0x7fffffff;
            #pragma unroll 1
            for (int w = 0; w < 8; ++w) {
                if (wavemax[w][tok] < thr) continue;
                unsigned long long mm = cmask[w][tok];
                while (mm) {
                    const int bit = __builtin_ctzll(mm); mm &= mm - 1;
                    const int k = w * 64 + bit;
                    double dl = xl - (double)W[k * 64 + l];
                    double p = dl * dl;
                    #pragma unroll
                    for (int off = 1; off < 64; off <<= 1) p += __shfl_xor(p, off);
                    if (p < bd) { bd = p; bk = k; }   // ascending k + strict <
                }
            }
            if (l == 0) bkArr[tok] = bk;
        }
    }
    __syncthreads();

    // ---- epilogue: gather W rows (L2-hot), coalesced NCHW store ----
    {
        const int pp = tid & 127;            // token
        const int dq = tid >> 7;             // dim quarter 0..3
        const int kk = bkArr[pp];
        const float* wr = W + kk * 64 + dq * 16;
        float* ob = out + (size_t)b * 262144 + p0 + pp;
        #pragma unroll
        for (int j = 0; j < 4; ++j) {
            f32x4 v = *(const f32x4*)(wr + j * 4);
            ob[(size_t)(dq * 16 + j * 4 + 0) * HW_] = v[0];
            ob[(size_t)(dq * 16 + j * 4 + 1) * HW_] = v[1];
            ob[(size_t)(dq * 16 + j * 4 + 2) * HW_] = v[2];
            ob[(size_t)(dq * 16 + j * 4 + 3) * HW_] = v[3];
        }
    }
}

extern "C" void kernel_launch(void* const* d_in, const int* in_sizes, int n_in,
                              void* d_out, int out_size, void* d_ws, size_t ws_size,
                              hipStream_t stream) {
    const float* x = (const float*)d_in[0];
    const float* W = (const float*)d_in[1];
    unsigned short* Wb = (unsigned short*)d_ws;              // 64 KiB image
    float* nh = (float*)((char*)d_ws + 65536);               // 512 f32
    int* wmax2i = (int*)((char*)d_ws + 65536 + 2048);        // 1 int (float bits)
    hipMemsetAsync(wmax2i, 0, 4, stream);
    vq_prep<<<512, 64, 0, stream>>>(W, Wb, nh, wmax2i);
    vq_main<<<1024, 512, 0, stream>>>(x, W, Wb, nh, wmax2i, (float*)d_out);
}